// Round 1
// baseline (4379.688 us; speedup 1.0000x reference)
//
#include <hip/hip_runtime.h>
#include <math.h>

#define N_U 7
#define N_E 14
#define N_DET 16
#define N_FB 3
#define N_SV 256
#define N_PV 32
#define N_PAIR 196   // 14*14

__device__ __forceinline__ float tanh_fast(float x) {
    float e = __expf(2.0f * x);
    return 1.0f - __fdividef(2.0f, e + 1.0f);
}

extern "C" __global__ void __launch_bounds__(256, 2)
ansatz_kernel(const float* __restrict__ r_g,
              const float* __restrict__ s_w0, const float* __restrict__ s_b0,
              const float* __restrict__ s_w,  const float* __restrict__ s_b,
              const float* __restrict__ p_w0, const float* __restrict__ p_b0,
              const float* __restrict__ p_w,  const float* __restrict__ p_b,
              const float* __restrict__ va_w, const float* __restrict__ va_b,
              const float* __restrict__ wu_w, const float* __restrict__ wu_b,
              const float* __restrict__ wd_w, const float* __restrict__ wd_b,
              const float* __restrict__ wf_w, float* __restrict__ out)
{
    const int b = blockIdx.x;
    const int t = threadIdx.x;

    __shared__ float sv[N_E][N_SV];        // s-stream activations (residual carried)
    __shared__ float pv[N_PAIR][N_PV];     // p-stream activations
    __shared__ float mu_s[N_SV], md_s[N_SV];
    __shared__ float pu_s[N_E][N_PV], pd_s[N_E][N_PV];
    __shared__ float pw_s[N_PV * N_PV];
    __shared__ float pb_s[N_PV];
    __shared__ float sblk0[N_E][32];       // first-layer 32-wide feature block
    __shared__ float pin[N_PAIR][4];       // raw pair features
    __shared__ float envs[N_E];
    __shared__ float rbuf[N_E * 3];
    __shared__ float orb[2 * N_DET][49];   // 32 7x7 determinant matrices
    __shared__ float dsg[2 * N_DET], dld[2 * N_DET];

    // ---- load r ----
    if (t < N_E * 3) rbuf[t] = r_g[b * N_E * 3 + t];
    __syncthreads();

    // ---- raw features ----
    if (t < N_E) {
        float rx = rbuf[t * 3], ry = rbuf[t * 3 + 1], rz = rbuf[t * 3 + 2];
        float l0 = sqrtf(rx * rx + ry * ry + rz * rz);
        float z1 = rz - 1.4f;
        float l1 = sqrtf(rx * rx + ry * ry + z1 * z1);
        sblk0[t][0] = rx; sblk0[t][1] = ry; sblk0[t][2] = rz; sblk0[t][3] = l0;
        sblk0[t][4] = rx; sblk0[t][5] = ry; sblk0[t][6] = z1; sblk0[t][7] = l1;
        envs[t] = __expf(-l0) + __expf(-l1);
    }
    if (t < N_PAIR) {
        int i = t / N_E, j = t % N_E;
        float dx = rbuf[j * 3 + 0] - rbuf[i * 3 + 0];
        float dy = rbuf[j * 3 + 1] - rbuf[i * 3 + 1];
        float dz = rbuf[j * 3 + 2] - rbuf[i * 3 + 2];
        float ee = (i == j) ? 1.0f : 0.0f;
        float lx = dx + ee, ly = dy + ee, lz = dz + ee;
        float len = sqrtf(lx * lx + ly * ly + lz * lz);
        pin[t][0] = dx; pin[t][1] = dy; pin[t][2] = dz; pin[t][3] = len;
    }
    __syncthreads();

    // ---- first-layer fb_block means into sblk0 cols 8..31 ----
    if (t < 112) {
        int e = t / 8, k = t % 8;
        float su = 0.f, sd = 0.f;
        for (int i = 0; i < 7; i++)  su += sblk0[i][k];
        for (int i = 7; i < 14; i++) sd += sblk0[i][k];
        sblk0[e][8 + k]  = su * (1.f / 7.f);
        sblk0[e][16 + k] = sd * (1.f / 7.f);
    }
    if (t >= 128 && t < 128 + 56) {
        int q = t - 128; int j = q / 4, c = q % 4;
        float su = 0.f, sd = 0.f;
        for (int i = 0; i < 7; i++)  su += pin[i * N_E + j][c];
        for (int i = 7; i < 14; i++) sd += pin[i * N_E + j][c];
        sblk0[j][24 + c] = su * (1.f / 7.f);
        sblk0[j][28 + c] = sd * (1.f / 7.f);
    }
    __syncthreads();

    // ---- first s layer: sv = tanh(sblk0 @ s_w0 + s_b0) ----
    {
        const int n = t;
        float acc[N_E];
        float bias = s_b0[n];
        #pragma unroll
        for (int e = 0; e < N_E; e++) acc[e] = bias;
        for (int k = 0; k < 32; k += 4) {
            float w0 = s_w0[(k + 0) * N_SV + n];
            float w1 = s_w0[(k + 1) * N_SV + n];
            float w2 = s_w0[(k + 2) * N_SV + n];
            float w3 = s_w0[(k + 3) * N_SV + n];
            #pragma unroll
            for (int e = 0; e < N_E; e++) {
                float4 s4 = *(const float4*)&sblk0[e][k];
                acc[e] += s4.x * w0 + s4.y * w1 + s4.z * w2 + s4.w * w3;
            }
        }
        #pragma unroll
        for (int e = 0; e < N_E; e++) sv[e][n] = tanh_fast(acc[e]);
    }

    // ---- first p layer: pv = tanh(pin @ p_w0 + p_b0) ----
    {
        const int c = t & 31;
        float w0 = p_w0[c], w1 = p_w0[32 + c], w2 = p_w0[64 + c], w3 = p_w0[96 + c];
        float bias = p_b0[c];
        const int pr0 = t >> 5;
        #pragma unroll
        for (int m = 0; m < 25; m++) {
            int pair = pr0 + m * 8;
            if (pair < N_PAIR) {
                float4 q4 = *(const float4*)&pin[pair][0];
                float a = bias + q4.x * w0 + q4.y * w1 + q4.z * w2 + q4.w * w3;
                pv[pair][c] = tanh_fast(a);
            }
        }
    }
    __syncthreads();

    // ---- FB iterations (it<3: residual layers; it==3: final va layer) ----
    for (int it = 0; it <= N_FB; it++) {
        // means
        {
            const int n = t;
            float su = 0.f, sd = 0.f;
            #pragma unroll
            for (int e = 0; e < 7; e++)  su += sv[e][n];
            #pragma unroll
            for (int e = 7; e < 14; e++) sd += sv[e][n];
            mu_s[n] = su * (1.f / 7.f);
            md_s[n] = sd * (1.f / 7.f);
        }
        for (int idx = t; idx < N_E * N_PV; idx += 256) {
            int j = idx / N_PV, c = idx % N_PV;
            float su = 0.f, sd = 0.f;
            for (int i = 0; i < 7; i++)  su += pv[i * N_E + j][c];
            for (int i = 7; i < 14; i++) sd += pv[i * N_E + j][c];
            pu_s[j][c] = su * (1.f / 7.f);
            pd_s[j][c] = sd * (1.f / 7.f);
        }
        __syncthreads();

        const bool last = (it == N_FB);
        const float* W = last ? va_w : (s_w + it * 832 * N_SV);
        const float* B = last ? va_b : (s_b + it * N_SV);
        const int n = t;

        // shared base: mu @ W[256:512] + md @ W[512:768] + bias
        float base = B[n];
        for (int k = 0; k < N_SV; k += 4) {
            float4 m4 = *(const float4*)&mu_s[k];
            const float* Wk = W + (N_SV + k) * N_SV + n;
            base += m4.x * Wk[0] + m4.y * Wk[N_SV] + m4.z * Wk[2 * N_SV] + m4.w * Wk[3 * N_SV];
            float4 d4 = *(const float4*)&md_s[k];
            const float* Wk2 = W + (2 * N_SV + k) * N_SV + n;
            base += d4.x * Wk2[0] + d4.y * Wk2[N_SV] + d4.z * Wk2[2 * N_SV] + d4.w * Wk2[3 * N_SV];
        }

        float acc[N_E];
        #pragma unroll
        for (int e = 0; e < N_E; e++) acc[e] = base;

        // per-electron: sv @ W[0:256]
        for (int k = 0; k < N_SV; k += 4) {
            const float* Wk = W + k * N_SV + n;
            float w0 = Wk[0], w1 = Wk[N_SV], w2 = Wk[2 * N_SV], w3 = Wk[3 * N_SV];
            #pragma unroll
            for (int e = 0; e < N_E; e++) {
                float4 s4 = *(const float4*)&sv[e][k];
                acc[e] += s4.x * w0 + s4.y * w1 + s4.z * w2 + s4.w * w3;
            }
        }
        // per-electron: pu @ W[768:800], pd @ W[800:832]
        for (int k = 0; k < N_PV; k += 4) {
            const float* Wk = W + (3 * N_SV + k) * N_SV + n;
            float w0 = Wk[0], w1 = Wk[N_SV], w2 = Wk[2 * N_SV], w3 = Wk[3 * N_SV];
            #pragma unroll
            for (int e = 0; e < N_E; e++) {
                float4 q4 = *(const float4*)&pu_s[e][k];
                acc[e] += q4.x * w0 + q4.y * w1 + q4.z * w2 + q4.w * w3;
            }
            const float* Wk2 = W + (3 * N_SV + N_PV + k) * N_SV + n;
            float v0 = Wk2[0], v1 = Wk2[N_SV], v2 = Wk2[2 * N_SV], v3 = Wk2[3 * N_SV];
            #pragma unroll
            for (int e = 0; e < N_E; e++) {
                float4 q4 = *(const float4*)&pd_s[e][k];
                acc[e] += q4.x * v0 + q4.y * v1 + q4.z * v2 + q4.w * v3;
            }
        }

        float outv[N_E];
        #pragma unroll
        for (int e = 0; e < N_E; e++) {
            float th = tanh_fast(acc[e]);
            outv[e] = last ? th : (th + sv[e][n]);
        }
        __syncthreads();
        #pragma unroll
        for (int e = 0; e < N_E; e++) sv[e][n] = outv[e];
        __syncthreads();

        if (!last) {
            // p layer: pv = tanh(pv @ p_w[it] + p_b[it]) + pv
            for (int idx = t; idx < N_PV * N_PV; idx += 256)
                pw_s[idx] = p_w[it * N_PV * N_PV + idx];
            if (t < N_PV) pb_s[t] = p_b[it * N_PV + t];
            __syncthreads();

            const int c = t & 31;
            float wreg[N_PV];
            #pragma unroll
            for (int k = 0; k < N_PV; k++) wreg[k] = pw_s[k * N_PV + c];
            float bias = pb_s[c];
            float res[25];
            const int pr0 = t >> 5;
            #pragma unroll
            for (int m = 0; m < 25; m++) {
                int pair = pr0 + m * 8;
                if (pair < N_PAIR) {
                    float a = bias;
                    #pragma unroll
                    for (int k = 0; k < N_PV; k += 4) {
                        float4 q4 = *(const float4*)&pv[pair][k];
                        a += q4.x * wreg[k] + q4.y * wreg[k + 1] + q4.z * wreg[k + 2] + q4.w * wreg[k + 3];
                    }
                    res[m] = tanh_fast(a) + pv[pair][c];
                }
            }
            __syncthreads();
            #pragma unroll
            for (int m = 0; m < 25; m++) {
                int pair = pr0 + m * 8;
                if (pair < N_PAIR) pv[pair][c] = res[m];
            }
            __syncthreads();
        }
    }

    // ---- orbitals: sw = sv @ w{u,d}_w + b, scaled by env, scattered to det matrices ----
    for (int idx = t; idx < 2 * 784; idx += 256) {
        int sgrp = idx / 784;
        int rem  = idx % 784;
        int e    = rem / 112;
        int col  = rem % 112;
        const float* W  = sgrp ? wd_w : wu_w;
        const float* Bb = sgrp ? wd_b : wu_b;
        float a = Bb[col];
        const float* srow = sv[sgrp * 7 + e];
        for (int k = 0; k < N_SV; k += 4) {
            float4 s4 = *(const float4*)&srow[k];
            a += s4.x * W[(k + 0) * 112 + col] + s4.y * W[(k + 1) * 112 + col]
               + s4.z * W[(k + 2) * 112 + col] + s4.w * W[(k + 3) * 112 + col];
        }
        int o = col / 16, d = col % 16;
        orb[sgrp * 16 + d][o * 7 + e] = a * envs[sgrp * 7 + e];
    }
    __syncthreads();

    // ---- slogdet via LU with partial pivoting: one 7x7 det per thread ----
    if (t < 32) {
        float* A = orb[t];
        float sg = 1.0f, ld = 0.0f;
        for (int c0 = 0; c0 < 7; c0++) {
            int p = c0; float mx = fabsf(A[c0 * 7 + c0]);
            for (int rI = c0 + 1; rI < 7; rI++) {
                float v = fabsf(A[rI * 7 + c0]);
                if (v > mx) { mx = v; p = rI; }
            }
            if (p != c0) {
                for (int c2 = 0; c2 < 7; c2++) {
                    float tmp = A[c0 * 7 + c2]; A[c0 * 7 + c2] = A[p * 7 + c2]; A[p * 7 + c2] = tmp;
                }
                sg = -sg;
            }
            float piv = A[c0 * 7 + c0];
            if (piv < 0.f) sg = -sg;
            ld += __logf(fabsf(piv));
            float rp = 1.0f / piv;
            for (int rI = c0 + 1; rI < 7; rI++) {
                float f = A[rI * 7 + c0] * rp;
                for (int c2 = c0 + 1; c2 < 7; c2++) A[rI * 7 + c2] -= f * A[c0 * 7 + c2];
            }
        }
        dsg[t] = sg; dld[t] = ld;
    }
    __syncthreads();

    // ---- combine ----
    if (t == 0) {
        float ld[16], sg[16];
        float mx = -1e30f;
        #pragma unroll
        for (int d = 0; d < 16; d++) {
            ld[d] = dld[d] + dld[16 + d];
            sg[d] = dsg[d] * dsg[16 + d];
            mx = fmaxf(mx, ld[d]);
        }
        float psi = 0.f;
        #pragma unroll
        for (int d = 0; d < 16; d++) psi += sg[d] * __expf(ld[d] - mx) * wf_w[d];
        out[b] = __logf(fabsf(psi)) + mx;
    }
}

extern "C" void kernel_launch(void* const* d_in, const int* in_sizes, int n_in,
                              void* d_out, int out_size, void* d_ws, size_t ws_size,
                              hipStream_t stream) {
    (void)n_in; (void)d_ws; (void)ws_size; (void)out_size;
    const float* r    = (const float*)d_in[0];
    const float* s_w0 = (const float*)d_in[1];
    const float* s_b0 = (const float*)d_in[2];
    const float* s_w  = (const float*)d_in[3];
    const float* s_b  = (const float*)d_in[4];
    const float* p_w0 = (const float*)d_in[5];
    const float* p_b0 = (const float*)d_in[6];
    const float* p_w  = (const float*)d_in[7];
    const float* p_b  = (const float*)d_in[8];
    const float* va_w = (const float*)d_in[9];
    const float* va_b = (const float*)d_in[10];
    const float* wu_w = (const float*)d_in[11];
    const float* wu_b = (const float*)d_in[12];
    const float* wd_w = (const float*)d_in[13];
    const float* wd_b = (const float*)d_in[14];
    const float* wf_w = (const float*)d_in[15];
    float* out = (float*)d_out;

    const int nb = in_sizes[0] / (N_E * 3);
    hipLaunchKernelGGL(ansatz_kernel, dim3(nb), dim3(256), 0, stream,
                       r, s_w0, s_b0, s_w, s_b, p_w0, p_b0, p_w, p_b,
                       va_w, va_b, wu_w, wu_b, wd_w, wd_b, wf_w, out);
}

// Round 4
// 2579.830 us; speedup vs baseline: 1.6977x; 1.6977x over previous
//
#include <hip/hip_runtime.h>
#include <math.h>

#define N_U 7
#define N_E 14
#define N_DET 16
#define N_FB 3
#define N_SV 256
#define N_PV 32
#define N_PAIR 196   // 14*14

__device__ __forceinline__ float tanh_fast(float x) {
    float e = __expf(2.0f * x);
    return 1.0f - __fdividef(2.0f, e + 1.0f);
}

union SharedU {
    struct { float sblk0[N_E][32]; float pin[N_PAIR][4]; } a;  // first layer only (4928 B)
    float orb[2 * N_DET][49];                                  // epilogue only (6272 B)
};

extern "C" __global__ void __launch_bounds__(256, 3)
ansatz_kernel(const float* __restrict__ r_g,
              const float* __restrict__ s_w0, const float* __restrict__ s_b0,
              const float* __restrict__ s_w,  const float* __restrict__ s_b,
              const float* __restrict__ p_w0, const float* __restrict__ p_b0,
              const float* __restrict__ p_w,  const float* __restrict__ p_b,
              const float* __restrict__ va_w, const float* __restrict__ va_b,
              const float* __restrict__ wu_w, const float* __restrict__ wu_b,
              const float* __restrict__ wd_w, const float* __restrict__ wd_b,
              const float* __restrict__ wf_w, float* __restrict__ out)
{
    // XCD-aware bijective swizzle (gridDim.x % 8 == 0 for nb=4096)
    const int bid = blockIdx.x;
    const int nwg = gridDim.x;
    const int b = ((nwg & 7) == 0) ? ((bid & 7) * (nwg >> 3) + (bid >> 3)) : bid;
    const int t = threadIdx.x;

    __shared__ float sv[N_E][N_SV];                       // 14336 B
    __shared__ float pv[N_PAIR][N_PV];                    // 25088 B
    __shared__ float mu_s[N_SV], md_s[N_SV];              // 2048 B
    __shared__ float pu_s[N_E][N_PV], pd_s[N_E][N_PV];    // 3584 B
    __shared__ SharedU su;                                // 6272 B
    __shared__ float envs[N_E];
    __shared__ float rbuf[N_E * 3];
    __shared__ float dsg[2 * N_DET], dld[2 * N_DET];

    // ---- load r ----
    if (t < N_E * 3) rbuf[t] = r_g[b * N_E * 3 + t];
    __syncthreads();

    // ---- raw features ----
    if (t < N_E) {
        float rx = rbuf[t * 3], ry = rbuf[t * 3 + 1], rz = rbuf[t * 3 + 2];
        float l0 = sqrtf(rx * rx + ry * ry + rz * rz);
        float z1 = rz - 1.4f;
        float l1 = sqrtf(rx * rx + ry * ry + z1 * z1);
        su.a.sblk0[t][0] = rx; su.a.sblk0[t][1] = ry; su.a.sblk0[t][2] = rz; su.a.sblk0[t][3] = l0;
        su.a.sblk0[t][4] = rx; su.a.sblk0[t][5] = ry; su.a.sblk0[t][6] = z1; su.a.sblk0[t][7] = l1;
        envs[t] = __expf(-l0) + __expf(-l1);
    }
    if (t < N_PAIR) {
        int i = t / N_E, j = t % N_E;
        float dx = rbuf[j * 3 + 0] - rbuf[i * 3 + 0];
        float dy = rbuf[j * 3 + 1] - rbuf[i * 3 + 1];
        float dz = rbuf[j * 3 + 2] - rbuf[i * 3 + 2];
        float ee = (i == j) ? 1.0f : 0.0f;
        float lx = dx + ee, ly = dy + ee, lz = dz + ee;
        float len = sqrtf(lx * lx + ly * ly + lz * lz);
        su.a.pin[t][0] = dx; su.a.pin[t][1] = dy; su.a.pin[t][2] = dz; su.a.pin[t][3] = len;
    }
    __syncthreads();

    // ---- first-layer fb_block means into sblk0 cols 8..31 ----
    if (t < 112) {
        int e = t / 8, k = t % 8;
        float su_ = 0.f, sd_ = 0.f;
        for (int i = 0; i < 7; i++)  su_ += su.a.sblk0[i][k];
        for (int i = 7; i < 14; i++) sd_ += su.a.sblk0[i][k];
        su.a.sblk0[e][8 + k]  = su_ * (1.f / 7.f);
        su.a.sblk0[e][16 + k] = sd_ * (1.f / 7.f);
    }
    if (t >= 128 && t < 128 + 56) {
        int q = t - 128; int j = q / 4, c = q % 4;
        float su_ = 0.f, sd_ = 0.f;
        for (int i = 0; i < 7; i++)  su_ += su.a.pin[i * N_E + j][c];
        for (int i = 7; i < 14; i++) sd_ += su.a.pin[i * N_E + j][c];
        su.a.sblk0[j][24 + c] = su_ * (1.f / 7.f);
        su.a.sblk0[j][28 + c] = sd_ * (1.f / 7.f);
    }
    __syncthreads();

    // ---- first s layer: sv = tanh(sblk0 @ s_w0 + s_b0) ----
    {
        const int n = t;
        float acc[N_E];
        float bias = s_b0[n];
        #pragma unroll
        for (int e = 0; e < N_E; e++) acc[e] = bias;
        for (int k = 0; k < 32; k += 4) {
            float w0 = s_w0[(k + 0) * N_SV + n];
            float w1 = s_w0[(k + 1) * N_SV + n];
            float w2 = s_w0[(k + 2) * N_SV + n];
            float w3 = s_w0[(k + 3) * N_SV + n];
            #pragma unroll
            for (int e = 0; e < N_E; e++) {
                float4 s4 = *(const float4*)&su.a.sblk0[e][k];
                acc[e] += s4.x * w0 + s4.y * w1 + s4.z * w2 + s4.w * w3;
            }
        }
        #pragma unroll
        for (int e = 0; e < N_E; e++) sv[e][n] = tanh_fast(acc[e]);
    }

    // ---- first p layer: pv = tanh(pin @ p_w0 + p_b0) ----
    {
        const int c = t & 31, pr0 = t >> 5;
        float w0 = p_w0[c], w1 = p_w0[32 + c], w2 = p_w0[64 + c], w3 = p_w0[96 + c];
        float bias = p_b0[c];
        #pragma unroll
        for (int m = 0; m < 25; m++) {
            int pair = pr0 + (m << 3);
            if (pair < N_PAIR) {
                float4 q4 = *(const float4*)&su.a.pin[pair][0];
                pv[pair][c] = tanh_fast(bias + q4.x * w0 + q4.y * w1 + q4.z * w2 + q4.w * w3);
            }
        }
    }
    __syncthreads();

    // ---- FB iterations (it<3: residual layers; it==3: final va layer) ----
    for (int it = 0; it <= N_FB; it++) {
        // s-means: thread n reads its own column
        {
            const int n = t;
            float su_ = 0.f, sd_ = 0.f;
            #pragma unroll
            for (int e = 0; e < 7; e++)  su_ += sv[e][n];
            #pragma unroll
            for (int e = 7; e < 14; e++) sd_ += sv[e][n];
            mu_s[n] = su_ * (1.f / 7.f);
            md_s[n] = sd_ * (1.f / 7.f);
        }
        // p-means
        for (int idx = t; idx < N_E * N_PV; idx += 256) {
            int j = idx >> 5, c = idx & 31;
            float su_ = 0.f, sd_ = 0.f;
            for (int i = 0; i < 7; i++)  su_ += pv[i * N_E + j][c];
            for (int i = 7; i < 14; i++) sd_ += pv[i * N_E + j][c];
            pu_s[j][c] = su_ * (1.f / 7.f);
            pd_s[j][c] = sd_ * (1.f / 7.f);
        }
        __syncthreads();

        const bool last = (it == N_FB);
        const float* W = last ? va_w : (s_w + it * 832 * N_SV);
        const float* B = last ? va_b : (s_b + it * N_SV);
        const int n = t;

        // shared base: mu @ W[256:512] + md @ W[512:768] + bias
        float base = B[n];
        for (int k = 0; k < N_SV; k += 4) {
            float4 m4 = *(const float4*)&mu_s[k];
            const float* Wk = W + (N_SV + k) * N_SV + n;
            base += m4.x * Wk[0] + m4.y * Wk[N_SV] + m4.z * Wk[2 * N_SV] + m4.w * Wk[3 * N_SV];
            float4 d4 = *(const float4*)&md_s[k];
            const float* Wk2 = W + (2 * N_SV + k) * N_SV + n;
            base += d4.x * Wk2[0] + d4.y * Wk2[N_SV] + d4.z * Wk2[2 * N_SV] + d4.w * Wk2[3 * N_SV];
        }

        float acc[N_E];
        #pragma unroll
        for (int e = 0; e < N_E; e++) acc[e] = base;

        // per-electron: sv @ W[0:256]
        for (int k = 0; k < N_SV; k += 4) {
            const float* Wk = W + k * N_SV + n;
            float w0 = Wk[0], w1 = Wk[N_SV], w2 = Wk[2 * N_SV], w3 = Wk[3 * N_SV];
            #pragma unroll
            for (int e = 0; e < N_E; e++) {
                float4 s4 = *(const float4*)&sv[e][k];
                acc[e] += s4.x * w0 + s4.y * w1 + s4.z * w2 + s4.w * w3;
            }
        }
        // per-electron: pu @ W[768:800], pd @ W[800:832]
        for (int k = 0; k < N_PV; k += 4) {
            const float* Wk = W + (3 * N_SV + k) * N_SV + n;
            float w0 = Wk[0], w1 = Wk[N_SV], w2 = Wk[2 * N_SV], w3 = Wk[3 * N_SV];
            #pragma unroll
            for (int e = 0; e < N_E; e++) {
                float4 q4 = *(const float4*)&pu_s[e][k];
                acc[e] += q4.x * w0 + q4.y * w1 + q4.z * w2 + q4.w * w3;
            }
            const float* Wk2 = W + (3 * N_SV + N_PV + k) * N_SV + n;
            float v0 = Wk2[0], v1 = Wk2[N_SV], v2 = Wk2[2 * N_SV], v3 = Wk2[3 * N_SV];
            #pragma unroll
            for (int e = 0; e < N_E; e++) {
                float4 q4 = *(const float4*)&pd_s[e][k];
                acc[e] += q4.x * v0 + q4.y * v1 + q4.z * v2 + q4.w * v3;
            }
        }

        #pragma unroll
        for (int e = 0; e < N_E; e++) {
            float th = tanh_fast(acc[e]);
            acc[e] = last ? th : (th + sv[e][n]);
        }
        __syncthreads();
        #pragma unroll
        for (int e = 0; e < N_E; e++) sv[e][n] = acc[e];
        __syncthreads();

        if (!last) {
            // p layer: pv = tanh(pv @ p_w[it] + p_b[it]) + pv, 2 chunks of 98 pairs
            const int c = t & 31, pr0 = t >> 5;
            float wreg[N_PV];
            #pragma unroll
            for (int k = 0; k < N_PV; k++) wreg[k] = p_w[it * N_PV * N_PV + k * N_PV + c];
            const float bias = p_b[it * N_PV + c];

            #pragma unroll
            for (int ch = 0; ch < 2; ch++) {
                const int pbase = ch * 98;
                float res[13];
                #pragma unroll
                for (int m = 0; m < 13; m++) {
                    int q = pr0 + (m << 3);
                    if (q < 98) {
                        int pair = pbase + q;
                        float a = bias;
                        #pragma unroll
                        for (int k = 0; k < N_PV; k += 4) {
                            float4 q4 = *(const float4*)&pv[pair][k];
                            a += q4.x * wreg[k] + q4.y * wreg[k + 1] + q4.z * wreg[k + 2] + q4.w * wreg[k + 3];
                        }
                        res[m] = tanh_fast(a) + pv[pair][c];
                    }
                }
                __syncthreads();
                #pragma unroll
                for (int m = 0; m < 13; m++) {
                    int q = pr0 + (m << 3);
                    if (q < 98) pv[pbase + q][c] = res[m];
                }
                __syncthreads();
            }
        }
    }

    // ---- orbitals: sw = sv @ w{u,d}_w + b, scaled by env, scattered to det matrices ----
    for (int idx = t; idx < 2 * 784; idx += 256) {
        int sgrp = idx / 784;
        int rem  = idx % 784;
        int e    = rem / 112;
        int col  = rem % 112;
        const float* W  = sgrp ? wd_w : wu_w;
        const float* Bb = sgrp ? wd_b : wu_b;
        float a = Bb[col];
        const float* srow = sv[sgrp * 7 + e];
        for (int k = 0; k < N_SV; k += 4) {
            float4 s4 = *(const float4*)&srow[k];
            a += s4.x * W[(k + 0) * 112 + col] + s4.y * W[(k + 1) * 112 + col]
               + s4.z * W[(k + 2) * 112 + col] + s4.w * W[(k + 3) * 112 + col];
        }
        int o = col / 16, d = col % 16;
        su.orb[sgrp * 16 + d][o * 7 + e] = a * envs[sgrp * 7 + e];
    }
    __syncthreads();

    // ---- slogdet via LU with partial pivoting: one 7x7 det per thread ----
    if (t < 32) {
        float* A = su.orb[t];
        float sg = 1.0f, ld = 0.0f;
        for (int c0 = 0; c0 < 7; c0++) {
            int p = c0; float mx = fabsf(A[c0 * 7 + c0]);
            for (int rI = c0 + 1; rI < 7; rI++) {
                float v = fabsf(A[rI * 7 + c0]);
                if (v > mx) { mx = v; p = rI; }
            }
            if (p != c0) {
                for (int c2 = 0; c2 < 7; c2++) {
                    float tmp = A[c0 * 7 + c2]; A[c0 * 7 + c2] = A[p * 7 + c2]; A[p * 7 + c2] = tmp;
                }
                sg = -sg;
            }
            float piv = A[c0 * 7 + c0];
            if (piv < 0.f) sg = -sg;
            ld += __logf(fabsf(piv));
            float rp = 1.0f / piv;
            for (int rI = c0 + 1; rI < 7; rI++) {
                float f = A[rI * 7 + c0] * rp;
                for (int c2 = c0 + 1; c2 < 7; c2++) A[rI * 7 + c2] -= f * A[c0 * 7 + c2];
            }
        }
        dsg[t] = sg; dld[t] = ld;
    }
    __syncthreads();

    // ---- combine ----
    if (t == 0) {
        float mx = -1e30f;
        float ld[16], sg[16];
        #pragma unroll
        for (int d = 0; d < 16; d++) {
            ld[d] = dld[d] + dld[16 + d];
            sg[d] = dsg[d] * dsg[16 + d];
            mx = fmaxf(mx, ld[d]);
        }
        float psi = 0.f;
        #pragma unroll
        for (int d = 0; d < 16; d++) psi += sg[d] * __expf(ld[d] - mx) * wf_w[d];
        out[b] = __logf(fabsf(psi)) + mx;
    }
}

extern "C" void kernel_launch(void* const* d_in, const int* in_sizes, int n_in,
                              void* d_out, int out_size, void* d_ws, size_t ws_size,
                              hipStream_t stream) {
    (void)n_in; (void)d_ws; (void)ws_size; (void)out_size;
    const float* r    = (const float*)d_in[0];
    const float* s_w0 = (const float*)d_in[1];
    const float* s_b0 = (const float*)d_in[2];
    const float* s_w  = (const float*)d_in[3];
    const float* s_b  = (const float*)d_in[4];
    const float* p_w0 = (const float*)d_in[5];
    const float* p_b0 = (const float*)d_in[6];
    const float* p_w  = (const float*)d_in[7];
    const float* p_b  = (const float*)d_in[8];
    const float* va_w = (const float*)d_in[9];
    const float* va_b = (const float*)d_in[10];
    const float* wu_w = (const float*)d_in[11];
    const float* wu_b = (const float*)d_in[12];
    const float* wd_w = (const float*)d_in[13];
    const float* wd_b = (const float*)d_in[14];
    const float* wf_w = (const float*)d_in[15];
    float* out = (float*)d_out;

    const int nb = in_sizes[0] / (N_E * 3);
    hipLaunchKernelGGL(ansatz_kernel, dim3(nb), dim3(256), 0, stream,
                       r, s_w0, s_b0, s_w, s_b, p_w0, p_b0, p_w, p_b,
                       va_w, va_b, wu_w, wu_b, wd_w, wd_b, wf_w, out);
}